// Round 2
// baseline (381.530 us; speedup 1.0000x reference)
//
#include <hip/hip_runtime.h>

// PairwiseCost: out[b,i,j] = max(||x[b,i]||^2 + ||y[b,j]||^2 - 2<x[b,i],y[b,j]>, 0)
// B=16, N=2048, D=128, fp32 in/out. bf16 MFMA cross term, fp32-exact norms.
//
// R2: barrier-free main loop. The kernel is write-roofline-bound (268 MB out);
// R0/R1 convoy-stalled on store drains because prefetch-load consumption +
// __syncthreads forced vmcnt(0) every iteration (vmcnt is FIFO: waiting on a
// load drains all older stores). Fix:
//  - NO LDS staging of y: fragments are read straight from global each tile.
//    y is 1 MB/batch-slice -> fully L2-resident; re-read traffic ~0.5 TB at
//    L2 BW (~34 TB/s) ~ 15 us aggregate, hidden under the write stream.
//  - y norms in a 4 KB LDS buffer, computed once; ONE barrier per kernel.
//  - Per iteration: loads are issued and consumed BEFORE this iteration's
//    stores are issued, so a wave only ever drains its own previous-iter
//    stores -- which have had a whole iteration to retire. No block-level
//    convoy; waves drift and keep the write pipe continuously fed.
//  - Nontemporal output stores: don't evict L2-resident y with the 268 MB
//    write-once stream.
// Grid = 2 x 16 x 16 = 512 blocks = 2/CU (VGPR-limited, 8 waves/CU).

#define Bb   16
#define Nn   2048
#define Dd   128
#define TILE 128
#define JT   8     // j-tiles per block (128 x 1024 strip)

typedef __bf16 bf16x8 __attribute__((ext_vector_type(8)));
typedef float  f32x4  __attribute__((ext_vector_type(4)));

__device__ __forceinline__ bf16x8 pack8(float4 a, float4 b) {
  // compiler emits v_cvt_pk_bf16_f32 pairs (RTNE)
  bf16x8 r;
  r[0] = (__bf16)a.x; r[1] = (__bf16)a.y; r[2] = (__bf16)a.z; r[3] = (__bf16)a.w;
  r[4] = (__bf16)b.x; r[5] = (__bf16)b.y; r[6] = (__bf16)b.z; r[7] = (__bf16)b.w;
  return r;
}

__global__ __launch_bounds__(256, 2)
void pairwise_cost_kernel(const float* __restrict__ x,
                          const float* __restrict__ y,
                          float* __restrict__ out) {
  __shared__ float yn_s[TILE * JT];   // 4 KB: y row norms for the whole strip

  const int t  = threadIdx.x;
  const int b  = blockIdx.z;
  const int i0 = blockIdx.y * TILE;
  const int j0 = blockIdx.x * (TILE * JT);

  const int w    = t >> 6;
  const int lane = t & 63;
  const int lrow = lane & 15;       // fragment row (j for A / i for B)
  const int quad = lane >> 4;       // k-octet
  const int ib   = (w >> 1) * 64;   // wave's i-offset in the 128-row tile
  const int jb   = (w & 1) * 64;    // wave's j-offset in a 128-col j-tile

  // ---- prologue: y row norms for the 1024-row strip (fp32 exact) ----
  {
    const int r2 = t >> 1, half = t & 1;
    for (int g = 0; g < JT; ++g) {
      const float4* src =
          (const float4*)(y + ((size_t)b * Nn + j0 + g * TILE + r2) * Dd + half * 64);
      float ss = 0.f;
      #pragma unroll
      for (int q = 0; q < 16; ++q) {
        float4 v = src[q];
        ss += v.x * v.x + v.y * v.y + v.z * v.z + v.w * v.w;
      }
      ss += __shfl_xor(ss, 1);
      if (half == 0) yn_s[g * TILE + r2] = ss;
    }
  }

  // ---- prologue: x fragments + norms, registers only (once per block) ----
  bf16x8 xf[4][4];   // [ti][k]
  float  xn[4];
  {
    const float* xb = x + ((size_t)b * Nn + i0 + ib) * Dd;
    #pragma unroll
    for (int ti = 0; ti < 4; ++ti) {
      const float* rp = xb + (ti * 16 + lrow) * Dd + quad * 8;
      float ss = 0.f;
      #pragma unroll
      for (int k = 0; k < 4; ++k) {
        float4 u0 = *(const float4*)(rp + k * 32);
        float4 u1 = *(const float4*)(rp + k * 32 + 4);
        ss += u0.x * u0.x + u0.y * u0.y + u0.z * u0.z + u0.w * u0.w
            + u1.x * u1.x + u1.y * u1.y + u1.z * u1.z + u1.w * u1.w;
        xf[ti][k] = pack8(u0, u1);
      }
      ss += __shfl_xor(ss, 16);   // lane holds 32 of 128 elems; sum the 4 quads
      ss += __shfl_xor(ss, 32);
      xn[ti] = ss;
    }
  }
  __syncthreads();   // the ONLY barrier: yn_s ready

  float* outb = out + (size_t)b * Nn * Nn;

  for (int jt = 0; jt < JT; ++jt) {
    // (A) y fragments straight from global (L2-resident), convert to bf16
    bf16x8 yf[4][4];   // [k][tj]
    {
      const float* ybase = y + ((size_t)b * Nn + j0 + jt * TILE) * Dd;
      #pragma unroll
      for (int k = 0; k < 4; ++k)
        #pragma unroll
        for (int tj = 0; tj < 4; ++tj) {
          const float* rp = ybase + (jb + tj * 16 + lrow) * Dd + k * 32 + quad * 8;
          float4 u0 = *(const float4*)(rp);
          float4 u1 = *(const float4*)(rp + 4);
          yf[k][tj] = pack8(u0, u1);
        }
    }

    // (B) MFMA: swapped operands (A=y) => acc regs are 4 consecutive j
    f32x4 acc[4][4];
    #pragma unroll
    for (int ti = 0; ti < 4; ++ti)
      #pragma unroll
      for (int tj = 0; tj < 4; ++tj)
        acc[ti][tj] = (f32x4){0.f, 0.f, 0.f, 0.f};

    #pragma unroll
    for (int k = 0; k < 4; ++k)
      #pragma unroll
      for (int ti = 0; ti < 4; ++ti)
        #pragma unroll
        for (int tj = 0; tj < 4; ++tj)
          acc[ti][tj] = __builtin_amdgcn_mfma_f32_16x16x32_bf16(yf[k][tj], xf[ti][k],
                                                               acc[ti][tj], 0, 0, 0);

    // (C) epilogue: D layout col=lane&15 (i-sub), row=quad*4+rg (j-sub)
    //     float4 nontemporal stores, 4 consecutive j per lane
    #pragma unroll
    for (int ti = 0; ti < 4; ++ti) {
      const size_t orow =
          (size_t)(i0 + ib + ti * 16 + lrow) * Nn + (j0 + jt * TILE + jb);
      const float xnv = xn[ti];
      #pragma unroll
      for (int tj = 0; tj < 4; ++tj) {
        f32x4 yn4 = *(const f32x4*)&yn_s[jt * TILE + jb + tj * 16 + quad * 4];
        f32x4 a   = acc[ti][tj];
        f32x4 c;
        #pragma unroll
        for (int rg = 0; rg < 4; ++rg)
          c[rg] = fmaxf(xnv + yn4[rg] - 2.0f * a[rg], 0.0f);
        __builtin_nontemporal_store(c, (f32x4*)(outb + orow + tj * 16 + quad * 4));
      }
    }
  }
}

extern "C" void kernel_launch(void* const* d_in, const int* in_sizes, int n_in,
                              void* d_out, int out_size, void* d_ws, size_t ws_size,
                              hipStream_t stream) {
  const float* x = (const float*)d_in[0];
  const float* y = (const float*)d_in[1];
  float* out = (float*)d_out;
  dim3 grid(Nn / (TILE * JT), Nn / TILE, Bb);
  pairwise_cost_kernel<<<grid, dim3(256, 1, 1), 0, stream>>>(x, y, out);
}